// Round 5
// baseline (205.154 us; speedup 1.0000x reference)
//
#include <hip/hip_runtime.h>
#include <cstdint>
#include <cstddef>

// ---------------------------------------------------------------------------
// x = mean_i( softmax(q_i K^T / 16) ) @ h   with q = h@Wq, k = h@Wk
//   = sum_j c_j h_j,  c_j = (1/N) sum_i exp(e_ij)/l_i,  l_i = sum_j exp(e_ij)
//
// Round 5: locality, not data path. R2-R4 all hit ~50us/26% MfmaUtil with
// three different staging schemes -> bottleneck = 192 MB/pass of L3 re-reads
// (q evicts k from L2 continuously). Fix: XCD-hierarchical tiling.
//   xcd = bid&7 owns a 2048-row x 4096-col band: k band 2MB + q band 1MB stay
//   L2-resident; L3 traffic 24 MB/pass, L2 ~36 MB/XCD/pass (8.4us < MFMA 14us).
// Per-wave regs trimmed to ~160 (q 64 + 2 acc chains 32 + b pingpong 32) for
// 3 blocks/CU. exp via raw v_exp_f32 (2^x), log2e/16 folded into q at proj.
// softmax base change exact: 2^(1.4427*e) == e^(0.9999999998*e).
//
// ws: [0,4MB) q bf16 frag-major | [4MB,8MB) k frag-major | l fp32[8192] | c fp32[8192]
// Frag-major (32x32 MFMA A/B layout): elem (i,d) -> tile i>>5,
//   slot (d>>4)*64 + (i&31) + 32*((d>>3)&1), byte j = d&7; tile = 16 KB,
//   dword index within tile = a0*64 + lane  (lane-linear 16B).
// ---------------------------------------------------------------------------

#define N_ROWS 8192
#define DIM    256

typedef __bf16 bf16x8 __attribute__((ext_vector_type(8)));
typedef unsigned short u16x8 __attribute__((ext_vector_type(8)));
typedef float f32x16 __attribute__((ext_vector_type(16)));

__device__ __forceinline__ uint16_t f2bf(float f) {
    uint32_t u = __float_as_uint(f);
    uint32_t r = (u + 0x7fffu + ((u >> 16) & 1u)) >> 16;   // RTN-even
    return (uint16_t)r;
}

__device__ __forceinline__ float fexp2(float x) {
#if __has_builtin(__builtin_amdgcn_exp2f)
    return __builtin_amdgcn_exp2f(x);                      // v_exp_f32 = 2^x
#else
    return __expf(x * 0.69314718056f);
#endif
}

// ---------------------------------------------------------------------------
// Kernel 1: q = (h @ Wq) * (log2e/16), k = h @ Wk, bf16 frag-major.
// Grid 512: bid = rowtile*2 + which, 32 rows/block. h staged through LDS
// (coalesced global reads, stride-260 padding), W half staged coalesced,
// C repacked via LDS -> coalesced dwordx4 stores. Zero-inits l/c/out.
// ---------------------------------------------------------------------------
__global__ __launch_bounds__(256) void proj_kernel(
        const float* __restrict__ h, const float* __restrict__ Wq,
        const float* __restrict__ Wk, uint16_t* __restrict__ qf,
        uint16_t* __restrict__ kf, float* __restrict__ l_arr,
        float* __restrict__ c_arr, float* __restrict__ out) {
    __shared__ alignas(16) uint16_t wb[256 * 128];    // 64 KB, multi-purpose
    const int tid = threadIdx.x, lane = tid & 63, wave = tid >> 6;
    const int which = blockIdx.x & 1;
    const int rt = blockIdx.x >> 1;                   // 0..255 (32-row tiles)

    if (blockIdx.x < 32)       l_arr[blockIdx.x * 256 + tid] = 0.0f;
    else if (blockIdx.x < 64)  c_arr[(blockIdx.x - 32) * 256 + tid] = 0.0f;
    else if (blockIdx.x == 64) out[tid] = 0.0f;

    const float* __restrict__ W = which ? Wk : Wq;
    uint16_t* __restrict__ dst = which ? kf : qf;
    // q carries log2(e)/16 so the pass can use raw v_exp_f32 (base 2)
    const float scale = which ? 1.0f : (0.0625f * 1.44269504089f);

    // ---- stage h rows (32 x 256 fp32) into LDS, coalesced; stride 260 ----
    {
        float* hb = (float*)wb;
        for (int i = tid; i < 2048; i += 256) {
            int r = i >> 6, c = (i & 63) * 4;
            float4 v = *(const float4*)&h[(size_t)(rt * 32 + r) * DIM + c];
            *(float4*)&hb[r * 260 + c] = v;
        }
    }
    __syncthreads();

    // A-fragments: rows rt*32..+31, K=256 (32x32 A layout), bf16 in regs
    bf16x8 afrag[16];
    {
        const float* hb = (const float*)wb;
        const int r = lane & 31;
#pragma unroll
        for (int a0 = 0; a0 < 16; a0++) {
            const int c0 = a0 * 16 + (lane >> 5) * 8;
            float4 f0 = *(const float4*)&hb[r * 260 + c0];
            float4 f1 = *(const float4*)&hb[r * 260 + c0 + 4];
            u16x8 f;
            f[0] = f2bf(f0.x); f[1] = f2bf(f0.y); f[2] = f2bf(f0.z); f[3] = f2bf(f0.w);
            f[4] = f2bf(f1.x); f[5] = f2bf(f1.y); f[6] = f2bf(f1.z); f[7] = f2bf(f1.w);
            afrag[a0] = __builtin_bit_cast(bf16x8, f);
        }
    }

    for (int p = 0; p < 2; p++) {
        __syncthreads();                              // wb free (prev readers done)
#pragma unroll
        for (int c = 0; c < 32; c++) {                // coalesced float4 -> bf16
            int f = c * 256 + tid;                    // float4 index, 0..8191
            int k = f >> 5, nc = (f & 31) * 4;
            float4 w4 = *(const float4*)&W[(size_t)k * DIM + p * 128 + nc];
            ushort4 b;
            b.x = f2bf(w4.x); b.y = f2bf(w4.y); b.z = f2bf(w4.z); b.w = f2bf(w4.w);
            *(ushort4*)&wb[k * 128 + nc] = b;
        }
        __syncthreads();

        f32x16 acc;
#pragma unroll
        for (int i = 0; i < 16; i++) acc[i] = 0.0f;
        const int cl = wave * 32 + (lane & 31);       // local col in [0,128)
#pragma unroll
        for (int a0 = 0; a0 < 16; a0++) {
            const int kb = a0 * 16 + (lane >> 5) * 8;
            u16x8 f;
#pragma unroll
            for (int j = 0; j < 8; j++) f[j] = wb[(kb + j) * 128 + cl];
            acc = __builtin_amdgcn_mfma_f32_32x32x16_bf16(
                afrag[a0], __builtin_bit_cast(bf16x8, f), acc, 0, 0, 0);
        }
        __syncthreads();                              // all wb reads done

        // repack C-tile into frag layout via wave-private 2KB of wb
        {
            uint16_t* rp = &wb[wave * 2048];
            const int dcl = lane & 31;
            const int a0o = dcl >> 4, hi = (dcl >> 3) & 1, j = dcl & 7;
            const int ilb = 4 * (lane >> 5);
#pragma unroll
            for (int reg = 0; reg < 16; reg++) {
                int il = ilb + (reg & 3) + 8 * (reg >> 2);
                rp[(size_t)((a0o * 64) + il + 32 * hi) * 8 + j] =
                    f2bf(acc[reg] * scale);
            }
            const uint4* rv = (const uint4*)rp;       // wave-local RAW (lgkmcnt)
            uint4* gp = (uint4*)(dst + (size_t)rt * 8192 +
                                 (size_t)(p * 8 + wave * 2) * 512);
            gp[lane * 2]     = rv[lane * 2];
            gp[lane * 2 + 1] = rv[lane * 2 + 1];
        }
    }
}

// ---------------------------------------------------------------------------
// Kernels 2/3: two QK^T passes, XCD-tiled, barrier-free B path.
// Grid 512, 4 waves/block. xcd = bid&7 owns rows [xr*2048,+2048) x cols
// [xc*4096,+4096) (xr=xcd>>1, xc=xcd&1) -> k band 2MB + q band 1MB L2-hot.
// Within XCD: 16 row-blocks(128 rows) x 4 col-blocks(1024 cols).
// Wave: 1 rowtile q resident (64 regs), 32 col-tiles streamed via ping-pong
// quarter-buffers from global (L2), 2 acc chains (even/odd K).
// ---------------------------------------------------------------------------
template <int MODE>
__global__ __launch_bounds__(256, 3) void qk_pass(
        const uint16_t* __restrict__ qf, const uint16_t* __restrict__ kf,
        float* __restrict__ l_arr, float* __restrict__ c_arr) {
    __shared__ float c_lds[1024];                     // MODE 1 (4 KB)
    const int tid = threadIdx.x, lane = tid & 63, wave = tid >> 6;
    const int bid = blockIdx.x;
    const int xcd = bid & 7, w = bid >> 3;            // bid%8 -> XCD (heuristic)
    const int xr = xcd >> 1, xc = xcd & 1;
    const int rw = w & 15, cw = w >> 4;
    const int t0  = xr * 64 + rw * 4 + wave;          // q rowtile, 0..255
    const int ct0 = xc * 128 + cw * 32;               // first k coltile, 0..255
    const int row0 = t0 * 32;

    // resident q fragments: 1 rowtile x 16 K-chunks = 64 regs
    const uint4* qp = (const uint4*)qf;
    bf16x8 q[16];
#pragma unroll
    for (int a0 = 0; a0 < 16; a0++)
        q[a0] = __builtin_bit_cast(bf16x8, qp[(size_t)t0 * 1024 + a0 * 64 + lane]);

    float rs[16];   // MODE 0 row-sum partials
    float rr[16];   // MODE 1: 1/(N*l_i)
    if (MODE == 0) {
#pragma unroll
        for (int r = 0; r < 16; r++) rs[r] = 0.0f;
    } else {
#pragma unroll
        for (int r = 0; r < 16; r++) {
            int ro = (r & 3) + 8 * (r >> 2) + 4 * (lane >> 5);
            rr[r] = 1.0f / (8192.0f * l_arr[row0 + ro]);
        }
        for (int i = tid; i < 1024; i += 256) c_lds[i] = 0.0f;
        __syncthreads();
    }

    const uint4* kp = (const uint4*)kf;
    bf16x8 b[2][4];                                   // ping-pong quarter-buffers
    {
        const uint4* kt = kp + (size_t)ct0 * 1024;
#pragma unroll
        for (int i = 0; i < 4; i++)
            b[0][i] = __builtin_bit_cast(bf16x8, kt[i * 64 + lane]);
    }

    f32x16 ae, ao;                                    // 2 independent chains
#pragma unroll
    for (int i = 0; i < 16; i++) { ae[i] = 0.0f; ao[i] = 0.0f; }

    for (int t = 0; t < 32; t++) {
        const uint4* kt  = kp + (size_t)(ct0 + t) * 1024;
        const uint4* ktn = kt + 1024;
#pragma unroll
        for (int qd = 0; qd < 4; qd++) {
            const int cur = qd & 1, nxt = cur ^ 1;
            if (qd < 3) {                             // next quarter, this tile
#pragma unroll
                for (int i = 0; i < 4; i++)
                    b[nxt][i] = __builtin_bit_cast(bf16x8,
                        kt[((qd + 1) * 4 + i) * 64 + lane]);
            } else if (t < 31) {                      // quarter 0, next tile
#pragma unroll
                for (int i = 0; i < 4; i++)
                    b[nxt][i] = __builtin_bit_cast(bf16x8, ktn[i * 64 + lane]);
            }
            ae = __builtin_amdgcn_mfma_f32_32x32x16_bf16(q[qd * 4 + 0], b[cur][0], ae, 0, 0, 0);
            ao = __builtin_amdgcn_mfma_f32_32x32x16_bf16(q[qd * 4 + 1], b[cur][1], ao, 0, 0, 0);
            ae = __builtin_amdgcn_mfma_f32_32x32x16_bf16(q[qd * 4 + 2], b[cur][2], ae, 0, 0, 0);
            ao = __builtin_amdgcn_mfma_f32_32x32x16_bf16(q[qd * 4 + 3], b[cur][3], ao, 0, 0, 0);
        }
        // tile-t epilogue (next tile's quarter-0 loads already in flight)
        if (MODE == 0) {
#pragma unroll
            for (int r = 0; r < 16; r++) {
                rs[r] += fexp2(ae[r] + ao[r]);
                ae[r] = 0.0f;  ao[r] = 0.0f;
            }
        } else {
            float sv = 0.0f;
#pragma unroll
            for (int r = 0; r < 16; r++) {
                sv += fexp2(ae[r] + ao[r]) * rr[r];
                ae[r] = 0.0f;  ao[r] = 0.0f;
            }
            sv += __shfl_xor(sv, 32);                 // fold row halves per col
            if (lane < 32) atomicAdd(&c_lds[t * 32 + lane], sv);
        }
    }

    if (MODE == 0) {
#pragma unroll
        for (int r = 0; r < 16; r++) {
            float v = rs[r];
            v += __shfl_xor(v, 1);  v += __shfl_xor(v, 2);  v += __shfl_xor(v, 4);
            v += __shfl_xor(v, 8);  v += __shfl_xor(v, 16);
            if ((lane & 31) == 0) {
                int ro = (r & 3) + 8 * (r >> 2) + 4 * (lane >> 5);
                atomicAdd(&l_arr[row0 + ro], v);      // 8 blocks per row
            }
        }
    } else {
        __syncthreads();
        for (int i = tid; i < 1024; i += 256)
            atomicAdd(&c_arr[ct0 * 32 + i], c_lds[i]);
    }
}

// ---------------------------------------------------------------------------
// Kernel 4: x = c @ h. 128 blocks x 64 rows; coalesced h reads.
// ---------------------------------------------------------------------------
__global__ __launch_bounds__(256) void finish_kernel(
        const float* __restrict__ h, const float* __restrict__ c_arr,
        float* __restrict__ out) {
    const int d = threadIdx.x;
    const int j0 = blockIdx.x * 64;
    float acc = 0.0f;
    for (int j = j0; j < j0 + 64; j++) acc += c_arr[j] * h[(size_t)j * DIM + d];
    atomicAdd(&out[d], acc);
}

// ---------------------------------------------------------------------------
extern "C" void kernel_launch(void* const* d_in, const int* in_sizes, int n_in,
                              void* d_out, int out_size, void* d_ws, size_t ws_size,
                              hipStream_t stream) {
    const float* h  = (const float*)d_in[0];
    const float* Wq = (const float*)d_in[1];
    const float* Wk = (const float*)d_in[2];

    uint16_t* qf = (uint16_t*)d_ws;
    uint16_t* kf = qf + (size_t)N_ROWS * DIM;
    float* l_arr = (float*)((char*)d_ws + (size_t)8 * 1024 * 1024);
    float* c_arr = l_arr + N_ROWS;
    float* out = (float*)d_out;

    proj_kernel<<<512, 256, 0, stream>>>(h, Wq, Wk, qf, kf, l_arr, c_arr, out);
    qk_pass<0><<<512, 256, 0, stream>>>(qf, kf, l_arr, c_arr);
    qk_pass<1><<<512, 256, 0, stream>>>(qf, kf, l_arr, c_arr);
    finish_kernel<<<128, 256, 0, stream>>>(h, c_arr, out);
}

// Round 7
// 162.462 us; speedup vs baseline: 1.2628x; 1.2628x over previous
//
#include <hip/hip_runtime.h>
#include <cstdint>
#include <cstddef>

// ---------------------------------------------------------------------------
// x = mean_i( softmax(q_i K^T / 16) ) @ h   with q = h@Wq, k = h@Wk
//   = sum_j c_j h_j,  c_j = (1/N) sum_i exp(e_ij)/l_i,  l_i = sum_j exp(e_ij)
//
// Round 7: conservative merge after R6's NaN.
//  - proj_kernel: R5's verbatim (PASSING) version — W transposed in-kernel,
//    no wconv, ws layout identical to R5 (8,454,144 B high-water, proven).
//    R6's OOB-suspect: its +254KB ws footprint exceeded every passing round.
//  - qk_pass: R6's redesign kept (the perf theory under test): k-tile 16KB
//    staged ONCE per block via double-buffered global_load_lds (1 barrier/
//    tile), consumed by 4 waves x 2 rowtiles = 128 MFMA/tile. LDS port ~73%
//    of MFMA issue; L2 feed ~750KB/CU ~5us << MFMA floor 13.8us.
//
// ws: [0,4MB) q bf16 frag-major | [4MB,8MB) k frag-major | l fp32[8192] | c fp32[8192]
// Frag-major (32x32 MFMA A/B layout) per 32-row tile = 16 KB:
//   elem (i,d): tile i>>5, slot (d>>4)*64 + (i&31) + 32*((d>>3)&1), byte d&7;
//   dword-linear in (a0*64 + lane) -> coalesced dwordx4 / conflict-free b128.
// ---------------------------------------------------------------------------

#define N_ROWS 8192
#define DIM    256

typedef __bf16 bf16x8 __attribute__((ext_vector_type(8)));
typedef unsigned short u16x8 __attribute__((ext_vector_type(8)));
typedef float f32x16 __attribute__((ext_vector_type(16)));

__device__ __forceinline__ uint16_t f2bf(float f) {
    uint32_t u = __float_as_uint(f);
    uint32_t r = (u + 0x7fffu + ((u >> 16) & 1u)) >> 16;   // RTN-even
    return (uint16_t)r;
}

__device__ __forceinline__ float fexp2(float x) {
#if __has_builtin(__builtin_amdgcn_exp2f)
    return __builtin_amdgcn_exp2f(x);                      // v_exp_f32 = 2^x
#else
    return __expf(x * 0.69314718056f);
#endif
}

// async global->LDS, 16B/lane; lds dst is wave-uniform base + lane*16
__device__ __forceinline__ void gld16(const void* gsrc, void* ldst) {
    __builtin_amdgcn_global_load_lds(
        (const __attribute__((address_space(1))) unsigned int*)gsrc,
        (__attribute__((address_space(3))) unsigned int*)ldst, 16, 0, 0);
}

// ---------------------------------------------------------------------------
// Kernel 1 (R5 verbatim, PASSING): q = (h @ Wq)*(log2e/16), k = h @ Wk,
// bf16 frag-major. Grid 512: bid = rowtile*2 + which, 32 rows/block.
// h staged through LDS (stride-260), W half staged coalesced to LDS,
// C repacked via LDS -> coalesced dwordx4 stores. Zero-inits l/c/out.
// ---------------------------------------------------------------------------
__global__ __launch_bounds__(256) void proj_kernel(
        const float* __restrict__ h, const float* __restrict__ Wq,
        const float* __restrict__ Wk, uint16_t* __restrict__ qf,
        uint16_t* __restrict__ kf, float* __restrict__ l_arr,
        float* __restrict__ c_arr, float* __restrict__ out) {
    __shared__ alignas(16) uint16_t wb[256 * 128];    // 64 KB, multi-purpose
    const int tid = threadIdx.x, lane = tid & 63, wave = tid >> 6;
    const int which = blockIdx.x & 1;
    const int rt = blockIdx.x >> 1;                   // 0..255 (32-row tiles)

    if (blockIdx.x < 32)       l_arr[blockIdx.x * 256 + tid] = 0.0f;
    else if (blockIdx.x < 64)  c_arr[(blockIdx.x - 32) * 256 + tid] = 0.0f;
    else if (blockIdx.x == 64) out[tid] = 0.0f;

    const float* __restrict__ W = which ? Wk : Wq;
    uint16_t* __restrict__ dst = which ? kf : qf;
    // q carries log2(e)/16 so the pass can use raw v_exp_f32 (base 2)
    const float scale = which ? 1.0f : (0.0625f * 1.44269504089f);

    // ---- stage h rows (32 x 256 fp32) into LDS, coalesced; stride 260 ----
    {
        float* hb = (float*)wb;
        for (int i = tid; i < 2048; i += 256) {
            int r = i >> 6, c = (i & 63) * 4;
            float4 v = *(const float4*)&h[(size_t)(rt * 32 + r) * DIM + c];
            *(float4*)&hb[r * 260 + c] = v;
        }
    }
    __syncthreads();

    // A-fragments: rows rt*32..+31, K=256 (32x32 A layout), bf16 in regs
    bf16x8 afrag[16];
    {
        const float* hb = (const float*)wb;
        const int r = lane & 31;
#pragma unroll
        for (int a0 = 0; a0 < 16; a0++) {
            const int c0 = a0 * 16 + (lane >> 5) * 8;
            float4 f0 = *(const float4*)&hb[r * 260 + c0];
            float4 f1 = *(const float4*)&hb[r * 260 + c0 + 4];
            u16x8 f;
            f[0] = f2bf(f0.x); f[1] = f2bf(f0.y); f[2] = f2bf(f0.z); f[3] = f2bf(f0.w);
            f[4] = f2bf(f1.x); f[5] = f2bf(f1.y); f[6] = f2bf(f1.z); f[7] = f2bf(f1.w);
            afrag[a0] = __builtin_bit_cast(bf16x8, f);
        }
    }

    for (int p = 0; p < 2; p++) {
        __syncthreads();                              // wb free (prev readers done)
#pragma unroll
        for (int c = 0; c < 32; c++) {                // coalesced float4 -> bf16
            int f = c * 256 + tid;                    // float4 index, 0..8191
            int k = f >> 5, nc = (f & 31) * 4;
            float4 w4 = *(const float4*)&W[(size_t)k * DIM + p * 128 + nc];
            ushort4 b;
            b.x = f2bf(w4.x); b.y = f2bf(w4.y); b.z = f2bf(w4.z); b.w = f2bf(w4.w);
            *(ushort4*)&wb[k * 128 + nc] = b;
        }
        __syncthreads();

        f32x16 acc;
#pragma unroll
        for (int i = 0; i < 16; i++) acc[i] = 0.0f;
        const int cl = wave * 32 + (lane & 31);       // local col in [0,128)
#pragma unroll
        for (int a0 = 0; a0 < 16; a0++) {
            const int kb = a0 * 16 + (lane >> 5) * 8;
            u16x8 f;
#pragma unroll
            for (int j = 0; j < 8; j++) f[j] = wb[(kb + j) * 128 + cl];
            acc = __builtin_amdgcn_mfma_f32_32x32x16_bf16(
                afrag[a0], __builtin_bit_cast(bf16x8, f), acc, 0, 0, 0);
        }
        __syncthreads();                              // all wb reads done

        // repack C-tile into frag layout via wave-private 2KB of wb
        {
            uint16_t* rp = &wb[wave * 2048];
            const int dcl = lane & 31;
            const int a0o = dcl >> 4, hi = (dcl >> 3) & 1, j = dcl & 7;
            const int ilb = 4 * (lane >> 5);
#pragma unroll
            for (int reg = 0; reg < 16; reg++) {
                int il = ilb + (reg & 3) + 8 * (reg >> 2);
                rp[(size_t)((a0o * 64) + il + 32 * hi) * 8 + j] =
                    f2bf(acc[reg] * scale);
            }
            const uint4* rv = (const uint4*)rp;       // wave-local RAW (lgkmcnt)
            uint4* gp = (uint4*)(dst + (size_t)rt * 8192 +
                                 (size_t)(p * 8 + wave * 2) * 512);
            gp[lane * 2]     = rv[lane * 2];
            gp[lane * 2 + 1] = rv[lane * 2 + 1];
        }
    }
}

// ---------------------------------------------------------------------------
// Kernels 2/3 (R6 design): two QK^T passes. Grid 512 = 32 rowblocks(256 rows)
// x 16 colchunks(512 cols), 2 blocks/CU. k tile (32 cols, 16KB) staged to LDS
// once per block (double-buffered async global_load_lds, 1 barrier/tile),
// consumed by 4 waves x 2 rowtiles = 128 MFMAs/tile. q: 2 rowtiles/wave
// resident (128 regs). MODE 0: l_i row sums. MODE 1: c_j weighted col sums.
// ---------------------------------------------------------------------------
template <int MODE>
__global__ __launch_bounds__(256, 2) void qk_pass(
        const uint16_t* __restrict__ qf, const uint16_t* __restrict__ kf,
        float* __restrict__ l_arr, float* __restrict__ c_arr) {
    __shared__ alignas(16) uint16_t ktile[2][8192];   // 2 x 16 KB
    __shared__ float c_lds[512];
    const int tid = threadIdx.x, lane = tid & 63, wave = tid >> 6;
    const int bid = blockIdx.x;
    const int cc = bid & 15, rb = bid >> 4;
    const int t0 = rb * 8 + wave * 2;                 // wave's rowtiles t0, t0+1
    const int row0 = t0 * 32;

    // resident q: 2 rowtiles x 16 K-chunks = 128 regs
    const uint4* qp = (const uint4*)qf;
    bf16x8 q0[16], q1[16];
#pragma unroll
    for (int a0 = 0; a0 < 16; a0++) {
        q0[a0] = __builtin_bit_cast(bf16x8, qp[(size_t)t0 * 1024 + a0 * 64 + lane]);
        q1[a0] = __builtin_bit_cast(bf16x8, qp[(size_t)(t0 + 1) * 1024 + a0 * 64 + lane]);
    }

    float rs0[16], rs1[16];   // MODE 0 partials
    float rr0[16], rr1[16];   // MODE 1: 1/(N*l_i)
    if (MODE == 0) {
#pragma unroll
        for (int r = 0; r < 16; r++) { rs0[r] = 0.0f; rs1[r] = 0.0f; }
    } else {
#pragma unroll
        for (int r = 0; r < 16; r++) {
            int ro = (r & 3) + 8 * (r >> 2) + 4 * (lane >> 5);
            rr0[r] = 1.0f / (8192.0f * l_arr[row0 + ro]);
            rr1[r] = 1.0f / (8192.0f * l_arr[row0 + 32 + ro]);
        }
        for (int i = tid; i < 512; i += 256) c_lds[i] = 0.0f;
    }

    const char* ksrc = (const char*)kf + (size_t)cc * 16 * 16384;  // 16 tiles

    {   // prologue: stage tile 0 -> buffer 0
        const char* s0 = ksrc + wave * 4096 + lane * 16;
        char* d0 = (char*)&ktile[0][0] + wave * 4096;
#pragma unroll
        for (int it = 0; it < 4; it++) gld16(s0 + it * 1024, d0 + it * 1024);
    }

    for (int t = 0; t < 16; t++) {
        __syncthreads();          // vmcnt drained: tile t staged, and all
                                  // waves done reading the other buffer
        if (t < 15) {             // prefetch t+1; lands during this compute
            const char* sn = ksrc + (t + 1) * 16384 + wave * 4096 + lane * 16;
            char* dn = (char*)&ktile[(t + 1) & 1][0] + wave * 4096;
#pragma unroll
            for (int it = 0; it < 4; it++) gld16(sn + it * 1024, dn + it * 1024);
        }

        const uint16_t* kt = &ktile[t & 1][0];
        f32x16 acc0, acc1;        // 2 independent chains (one per rowtile)
#pragma unroll
        for (int i = 0; i < 16; i++) { acc0[i] = 0.0f; acc1[i] = 0.0f; }
#pragma unroll
        for (int a0 = 0; a0 < 16; a0++) {
            bf16x8 b = __builtin_bit_cast(bf16x8,
                *(const u16x8*)&kt[(size_t)(a0 * 64 + lane) * 8]);
            acc0 = __builtin_amdgcn_mfma_f32_32x32x16_bf16(q0[a0], b, acc0, 0, 0, 0);
            acc1 = __builtin_amdgcn_mfma_f32_32x32x16_bf16(q1[a0], b, acc1, 0, 0, 0);
        }

        if (MODE == 0) {
#pragma unroll
            for (int r = 0; r < 16; r++) {
                rs0[r] += fexp2(acc0[r]);
                rs1[r] += fexp2(acc1[r]);
            }
        } else {
            float sv = 0.0f;
#pragma unroll
            for (int r = 0; r < 16; r++) {
                sv += fexp2(acc0[r]) * rr0[r];
                sv += fexp2(acc1[r]) * rr1[r];
            }
            sv += __shfl_xor(sv, 32);                 // fold row halves per col
            if (lane < 32) atomicAdd(&c_lds[t * 32 + lane], sv);
        }
    }

    if (MODE == 0) {
#pragma unroll
        for (int r = 0; r < 16; r++) {
            float v0 = rs0[r], v1 = rs1[r];
            v0 += __shfl_xor(v0, 1);  v0 += __shfl_xor(v0, 2);
            v0 += __shfl_xor(v0, 4);  v0 += __shfl_xor(v0, 8);
            v0 += __shfl_xor(v0, 16);
            v1 += __shfl_xor(v1, 1);  v1 += __shfl_xor(v1, 2);
            v1 += __shfl_xor(v1, 4);  v1 += __shfl_xor(v1, 8);
            v1 += __shfl_xor(v1, 16);
            if ((lane & 31) == 0) {
                int ro = (r & 3) + 8 * (r >> 2) + 4 * (lane >> 5);
                atomicAdd(&l_arr[row0 + ro], v0);
                atomicAdd(&l_arr[row0 + 32 + ro], v1);
            }
        }
    } else {
        __syncthreads();
        for (int i = tid; i < 512; i += 256)
            atomicAdd(&c_arr[cc * 512 + i], c_lds[i]);
    }
}

// ---------------------------------------------------------------------------
// Kernel 4: x = c @ h. 128 blocks x 64 rows; coalesced h reads.
// ---------------------------------------------------------------------------
__global__ __launch_bounds__(256) void finish_kernel(
        const float* __restrict__ h, const float* __restrict__ c_arr,
        float* __restrict__ out) {
    const int d = threadIdx.x;
    const int j0 = blockIdx.x * 64;
    float acc = 0.0f;
    for (int j = j0; j < j0 + 64; j++) acc += c_arr[j] * h[(size_t)j * DIM + d];
    atomicAdd(&out[d], acc);
}

// ---------------------------------------------------------------------------
extern "C" void kernel_launch(void* const* d_in, const int* in_sizes, int n_in,
                              void* d_out, int out_size, void* d_ws, size_t ws_size,
                              hipStream_t stream) {
    const float* h  = (const float*)d_in[0];
    const float* Wq = (const float*)d_in[1];
    const float* Wk = (const float*)d_in[2];

    // ws layout identical to R5 (proven high-water 8,454,144 B)
    uint16_t* qf = (uint16_t*)d_ws;
    uint16_t* kf = qf + (size_t)N_ROWS * DIM;                  // +4 MB
    float* l_arr = (float*)((char*)d_ws + (size_t)8 * 1024 * 1024);
    float* c_arr = l_arr + N_ROWS;
    float* out = (float*)d_out;

    proj_kernel<<<512, 256, 0, stream>>>(h, Wq, Wk, qf, kf, l_arr, c_arr, out);
    qk_pass<0><<<512, 256, 0, stream>>>(qf, kf, l_arr, c_arr);
    qk_pass<1><<<512, 256, 0, stream>>>(qf, kf, l_arr, c_arr);
    finish_kernel<<<128, 256, 0, stream>>>(h, c_arr, out);
}